// Round 10
// baseline (220.866 us; speedup 1.0000x reference)
//
#include <hip/hip_runtime.h>

static constexpr int kNE = 50000;
static constexpr int kNR = 1000;
static constexpr int kE  = 800000;
static constexpr int kEH = 256;
static constexpr int kRH = 64;
static constexpr float kNeg = 0.01f;

static constexpr int kSegsPerB = 64;                       // 6-bit local seg
static constexpr int kSegs = 2 * kNE;                      // head segs then tail segs
static constexpr int kB = (kSegs + kSegsPerB - 1) / kSegsPerB;   // 1563 buckets
static constexpr int kCap = 1536;                          // per-bucket capacity (mean 1024)
static constexpr int kGrid = 256;                          // 1 block/CU -> co-residency guaranteed
static constexpr int kThr  = 512;
static constexpr int kEdgesPerBlk = (kE + kGrid - 1) / kGrid;   // 3125
static constexpr int kRecsPerBlk  = 2 * kEdgesPerBlk;           // 6250
static constexpr int kCntPad = 2048;

__device__ __forceinline__ float lrelu(float x){ return x > 0.f ? x : kNeg * x; }

// LDS layout (byte offsets into smem):
// phase 1: cnt[2048]i @0..8192 | cur[2048]i @8192..16384 | srt[6272]u @16384..41472
// phase 2: srl[1000]f @0 | sn[64]f @4096 | cnt2 @4352 | start2 @4608 | cur2 @4864
//          relbuf[1536]us @5120..8192 | alphabuf[1536]f @8192..14336
static constexpr int kSmemBytes = 41472;

__global__ __launch_bounds__(kThr, 2) void k_fused(
        const float* __restrict__ xe, const float* __restrict__ ahw,
        const float* __restrict__ atw, const float* __restrict__ xr,
        const float* __restrict__ arw,
        const int* __restrict__ head, const int* __restrict__ tail,
        const int* __restrict__ rel,
        float* __restrict__ s_h, float* __restrict__ s_t, float* __restrict__ s_r,
        int* __restrict__ bucket_fill, unsigned short* __restrict__ records,
        int* __restrict__ bar, int* __restrict__ flag,
        float* __restrict__ out){
    __shared__ __align__(16) unsigned char smem[kSmemBytes];
    __shared__ int wsum[8];

    int* cnt = (int*)smem;
    int* cur = (int*)(smem + 8192);
    unsigned int* srt = (unsigned int*)(smem + 16384);

    int tid  = threadIdx.x;
    int lane = tid & 63;
    int wave = tid >> 6;

    // ================= phase 1: bin this block's edge chunk + scores =================
    for (int i = tid; i < kCntPad; i += kThr) cnt[i] = 0;
    __syncthreads();

    int e0 = blockIdx.x * kEdgesPerBlk;
    int eend = min(kE, e0 + kEdgesPerBlk);

    // rc32 = (seg<<10)|rel ; bucket = rc32>>16 ; payload low16 = (seglocal<<10)|rel
    unsigned int recs[14];
    #pragma unroll
    for (int p = 0; p < 7; ++p){
        int e = e0 + p * kThr + tid;
        unsigned int rh = 0xFFFFFFFFu, rt = 0xFFFFFFFFu;
        if (e < eend){
            int h = head[e], t = tail[e], r = rel[e];
            rh = ((unsigned int)h << 10) | (unsigned int)r;
            rt = ((unsigned int)(kNE + t) << 10) | (unsigned int)r;
            atomicAdd(&cnt[rh >> 16], 1);
            atomicAdd(&cnt[rt >> 16], 1);
        }
        recs[p] = rh; recs[7 + p] = rt;
    }

    // node + rel scores, grid-strided by global wave (overlaps bin LDS atomics)
    {
        int gw = blockIdx.x * 8 + wave;            // 0..2047
        for (int node = gw; node < kNE; node += kGrid * 8){
            const float4* row = (const float4*)(xe + (size_t)node * kEH);
            float4 xv = row[lane];
            float4 av = ((const float4*)ahw)[lane];
            float4 bv = ((const float4*)atw)[lane];
            float ph = xv.x*av.x + xv.y*av.y + xv.z*av.z + xv.w*av.w;
            float pt = xv.x*bv.x + xv.y*bv.y + xv.z*bv.z + xv.w*bv.w;
            #pragma unroll
            for (int o = 32; o > 0; o >>= 1){
                ph += __shfl_down(ph, o, 64);
                pt += __shfl_down(pt, o, 64);
            }
            if (lane == 0){ s_h[node] = ph; s_t[node] = pt; }
        }
        for (int r = gw; r < kNR; r += kGrid * 8){
            float p = xr[(size_t)r * kRH + lane] * arw[lane];
            #pragma unroll
            for (int o = 32; o > 0; o >>= 1) p += __shfl_down(p, o, 64);
            if (lane == 0) s_r[r] = p;
        }
    }
    __syncthreads();

    // exclusive scan over cnt[2048]: thread owns 4t..4t+3; wave shuffle-scan + wave prefix
    int c0 = cnt[4 * tid], c1 = cnt[4 * tid + 1], c2 = cnt[4 * tid + 2], c3 = cnt[4 * tid + 3];
    int v = c0 + c1 + c2 + c3;
    int x = v;
    #pragma unroll
    for (int o = 1; o < 64; o <<= 1){
        int y = __shfl_up(x, o, 64);
        if (lane >= o) x += y;
    }
    if (lane == 63) wsum[wave] = x;
    __syncthreads();
    int wpre = 0, tot = 0;
    #pragma unroll
    for (int w = 0; w < 8; ++w){
        int s = wsum[w];
        if (w < wave) wpre += s;
        tot += s;
    }
    int base = wpre + x - v;
    cur[4 * tid]     = base;
    cur[4 * tid + 1] = base + c0;
    cur[4 * tid + 2] = base + c0 + c1;
    cur[4 * tid + 3] = base + c0 + c1 + c2;
    __syncthreads();

    // scatter into bucket-sorted LDS order
    #pragma unroll
    for (int p = 0; p < 14; ++p){
        unsigned int rc = recs[p];
        if (rc != 0xFFFFFFFFu){
            int slot = atomicAdd(&cur[rc >> 16], 1);
            srt[slot] = rc;
        }
    }
    __syncthreads();

    // reserve global runs; cur[bk] := gbase - start[bk]  (start = cur - cnt)
    for (int i = tid; i < kB; i += kThr){
        int c = cnt[i];
        if (c > 0){
            int gb = atomicAdd(&bucket_fill[i], c);
            cur[i] = gb - (cur[i] - c);
        }
    }
    __syncthreads();

    // coalesced write-out of sorted runs (2-byte payloads)
    for (int j = tid; j < tot; j += kThr){
        unsigned int rc = srt[j];
        int bk = rc >> 16;
        int g  = cur[bk] + j;
        if (g < kCap) records[(size_t)bk * kCap + g] = (unsigned short)(rc & 0xFFFFu);
    }

    // ================= grid barrier (device-scope; all 256 blocks co-resident) =================
    __syncthreads();
    if (tid == 0){
        __threadfence();
        int prev = atomicAdd(bar, 1);
        if (prev == (int)gridDim.x - 1){
            __threadfence();
            atomicExch(flag, 1);
        } else {
            while (atomicAdd(flag, 0) == 0){ __builtin_amdgcn_s_sleep(8); }
        }
        __threadfence();
    }
    __syncthreads();

    // ================= phase 2: per-bucket sort + softmax + aggregate =================
    float* srl   = (float*)smem;                       // [1000]
    float* sn    = (float*)(smem + 4096);              // [64]
    int* cnt2    = (int*)(smem + 4352);                // [64]
    int* start2  = (int*)(smem + 4608);                // [64]
    int* cur2    = (int*)(smem + 4864);                // [64]
    unsigned short* relbuf = (unsigned short*)(smem + 5120);   // [1536]
    float* alphabuf = (float*)(smem + 8192);           // [1536]

    for (int i = tid; i < kNR; i += kThr) srl[i] = s_r[i];

    for (int bk = blockIdx.x; bk < kB; bk += kGrid){
        __syncthreads();   // protect relbuf/alphabuf reuse + srl first-load
        if (tid < kSegsPerB){
            cnt2[tid] = 0;
            int gseg = bk * kSegsPerB + tid;
            float s = 0.f;
            if (gseg < kNE) s = s_h[gseg];
            else if (gseg < kSegs) s = s_t[gseg - kNE];
            sn[tid] = s;
        }
        __syncthreads();

        int nrec = bucket_fill[bk];
        if (nrec > kCap) nrec = kCap;
        const unsigned short* rb = records + (size_t)bk * kCap;

        unsigned short rr3[3];
        #pragma unroll
        for (int p = 0; p < 3; ++p){
            int idx = p * kThr + tid;
            unsigned short rc = 0xFFFFu;
            if (idx < nrec){
                rc = rb[idx];
                atomicAdd(&cnt2[rc >> 10], 1);
            }
            rr3[p] = rc;
        }
        __syncthreads();
        // single-wave shuffle scan over 64 counters
        if (tid < kSegsPerB){
            int c = cnt2[tid];
            int xx = c;
            #pragma unroll
            for (int o = 1; o < 64; o <<= 1){
                int y = __shfl_up(xx, o, 64);
                if (tid >= o) xx += y;
            }
            int s = xx - c;
            start2[tid] = s;
            cur2[tid] = s;
        }
        __syncthreads();
        // scatter rel ids into seg-grouped LDS order, logits inline
        #pragma unroll
        for (int p = 0; p < 3; ++p){
            unsigned short rc = rr3[p];
            if (rc != 0xFFFFu){
                int ls = rc >> 10;
                int rv = rc & 1023;
                int slot = atomicAdd(&cur2[ls], 1);
                relbuf[slot] = (unsigned short)rv;
                alphabuf[slot] = lrelu(sn[ls] + srl[rv]);
            }
        }
        __syncthreads();

        // fused softmax + aggregate: 16-lane group per segment (32 groups)
        int grp = tid >> 4;        // 0..31
        int sub = tid & 15;        // feature quad / stride
        for (int ls = grp; ls < kSegsPerB; ls += 32){
            int gseg = bk * kSegsPerB + ls;
            if (gseg >= kSegs) break;
            int deg = cnt2[ls], st = start2[ls];

            float part = -INFINITY;
            for (int k = sub; k < deg; k += 16) part = fmaxf(part, alphabuf[st + k]);
            #pragma unroll
            for (int o = 1; o < 16; o <<= 1) part = fmaxf(part, __shfl_xor(part, o, 64));
            float m = part;

            float ssum = 0.f;
            for (int k = sub; k < deg; k += 16){
                float e = __expf(alphabuf[st + k] - m);
                alphabuf[st + k] = e;
                ssum += e;
            }
            #pragma unroll
            for (int o = 1; o < 16; o <<= 1) ssum += __shfl_xor(ssum, o, 64);
            float inv = 1.f / (ssum + 1e-16f);

            float4 acc = {0.f, 0.f, 0.f, 0.f};
            int k = 0;
            for (; k + 4 <= deg; k += 4){
                int r0 = relbuf[st + k],     r1 = relbuf[st + k + 1];
                int r2 = relbuf[st + k + 2], r3 = relbuf[st + k + 3];
                float a0 = alphabuf[st + k] * inv,     a1 = alphabuf[st + k + 1] * inv;
                float a2 = alphabuf[st + k + 2] * inv, a3 = alphabuf[st + k + 3] * inv;
                float4 v0 = ((const float4*)(xr + (size_t)r0 * kRH))[sub];
                float4 v1 = ((const float4*)(xr + (size_t)r1 * kRH))[sub];
                float4 v2 = ((const float4*)(xr + (size_t)r2 * kRH))[sub];
                float4 v3 = ((const float4*)(xr + (size_t)r3 * kRH))[sub];
                acc.x += a0*v0.x + a1*v1.x + a2*v2.x + a3*v3.x;
                acc.y += a0*v0.y + a1*v1.y + a2*v2.y + a3*v3.y;
                acc.z += a0*v0.z + a1*v1.z + a2*v2.z + a3*v3.z;
                acc.w += a0*v0.w + a1*v1.w + a2*v2.w + a3*v3.w;
            }
            for (; k < deg; ++k){
                int rv = relbuf[st + k];
                float a = alphabuf[st + k] * inv;
                float4 vv = ((const float4*)(xr + (size_t)rv * kRH))[sub];
                acc.x += a*vv.x; acc.y += a*vv.y; acc.z += a*vv.z; acc.w += a*vv.w;
            }
            bool isHead = gseg < kNE;
            int node = isHead ? gseg : gseg - kNE;
            float4* op = (float4*)(out + (size_t)node * (2 * kRH) + (isHead ? 0 : kRH));
            op[sub] = acc;
        }
    }
}

extern "C" void kernel_launch(void* const* d_in, const int* in_sizes, int n_in,
                              void* d_out, int out_size, void* d_ws, size_t ws_size,
                              hipStream_t stream) {
    const float* xe  = (const float*)d_in[0];    // [50000,256] f32
    const float* xr  = (const float*)d_in[1];    // [1000,64]   f32
    const int* edge_index = (const int*)d_in[2]; // [2,800000]
    const int* rel        = (const int*)d_in[3]; // [800000]
    const float* ahw = (const float*)d_in[6];    // [256]
    const float* atw = (const float*)d_in[7];    // [256]
    const float* arw = (const float*)d_in[8];    // [64]
    float* out = (float*)d_out;                  // [50000,128] f32

    const int* head = edge_index;
    const int* tail = edge_index + kE;

    char* ws = (char*)d_ws;
    float* s_h  = (float*)ws;                    ws += kNE * sizeof(float);
    float* s_t  = (float*)ws;                    ws += kNE * sizeof(float);
    float* s_r  = (float*)ws;                    ws += kNR * sizeof(float);
    int*   bucket_fill = (int*)ws;               ws += (kB + 2) * sizeof(int);
    int*   bar  = bucket_fill + kB;
    int*   flag = bucket_fill + kB + 1;
    ws = (char*)(((size_t)ws + 255) & ~(size_t)255);
    unsigned short* records = (unsigned short*)ws; ws += (size_t)kB * kCap * sizeof(unsigned short);

    hipMemsetAsync(bucket_fill, 0, (kB + 2) * sizeof(int), stream);
    k_fused<<<kGrid, kThr, 0, stream>>>(xe, ahw, atw, xr, arw, head, tail, rel,
                                        s_h, s_t, s_r, bucket_fill, records,
                                        bar, flag, out);
}